// Round 1
// baseline (370.971 us; speedup 1.0000x reference)
//
#include <hip/hip_runtime.h>
#include <math.h>

#define DD 64
#define HH 8
#define DHH 8
#define NN 512
#define LL 1024
#define EPSF 1e-5f

// ---------------------------------------------------------------------------
// Kernel A: per (n,l) row: LayerNorm, k = x@Wk, v = x@Wv; per-l mean of x.
// grid = L blocks, 256 threads; thread t handles rows n = t and n = 256+t.
// k,v stored transposed as (L, N, 8) so kernel B reads contiguous slices.
// ---------------------------------------------------------------------------
__global__ __launch_bounds__(256) void kA(
    const float* __restrict__ msa, const float* __restrict__ lnw, const float* __restrict__ lnb,
    const float* __restrict__ Wk, const float* __restrict__ Wv,
    float* __restrict__ kb, float* __restrict__ vb, float* __restrict__ xbar)
{
  __shared__ float red[DD * 257];   // 65.8 KB, stride 257 -> conflict-free column sums
  const int l = blockIdx.x;
  const int t = threadIdx.x;

  float xacc[DD];
#pragma unroll
  for (int d = 0; d < DD; ++d) xacc[d] = 0.f;

#pragma unroll
  for (int rep = 0; rep < 2; ++rep) {
    const int n = rep * 256 + t;
    const float4* rowp = (const float4*)(msa + ((size_t)n * LL + l) * DD);
    float row[DD];
#pragma unroll
    for (int i = 0; i < 16; ++i) {
      float4 f = rowp[i];
      row[4*i+0] = f.x; row[4*i+1] = f.y; row[4*i+2] = f.z; row[4*i+3] = f.w;
    }
    float s = 0.f;
#pragma unroll
    for (int d = 0; d < DD; ++d) s += row[d];
    const float mu = s * (1.f / DD);
    float s2 = 0.f;
#pragma unroll
    for (int d = 0; d < DD; ++d) { float c = row[d] - mu; s2 = fmaf(c, c, s2); }
    const float rs = rsqrtf(s2 * (1.f / DD) + EPSF);

    float ka[DHH], va[DHH];
#pragma unroll
    for (int j = 0; j < DHH; ++j) { ka[j] = 0.f; va[j] = 0.f; }
#pragma unroll
    for (int d = 0; d < DD; ++d) {
      const float xn = (row[d] - mu) * rs * lnw[d] + lnb[d];
      xacc[d] += xn;
#pragma unroll
      for (int j = 0; j < DHH; ++j) {
        ka[j] = fmaf(xn, Wk[d*DHH + j], ka[j]);
        va[j] = fmaf(xn, Wv[d*DHH + j], va[j]);
      }
    }
    float4* kp = (float4*)(kb + ((size_t)l * NN + n) * DHH);
    float4* vp = (float4*)(vb + ((size_t)l * NN + n) * DHH);
    kp[0] = make_float4(ka[0], ka[1], ka[2], ka[3]);
    kp[1] = make_float4(ka[4], ka[5], ka[6], ka[7]);
    vp[0] = make_float4(va[0], va[1], va[2], va[3]);
    vp[1] = make_float4(va[4], va[5], va[6], va[7]);
  }

  // block-wide reduction of xacc -> xbar[l][*]
#pragma unroll
  for (int d = 0; d < DD; ++d) red[d*257 + t] = xacc[d];
  __syncthreads();
  if (t < DD) {
    float s = 0.f;
    for (int i = 0; i < 256; ++i) s += red[t*257 + i];
    xbar[(size_t)l * DD + t] = s * (1.f / NN);
  }
}

// ---------------------------------------------------------------------------
// Kernel B: per l: q = xbar@Wq (scaled), scores over n, softmax, o = attn@v.
// grid = L blocks, 512 threads = 8 waves; wave h owns head h.
// ---------------------------------------------------------------------------
__global__ __launch_bounds__(512) void kB(
    const float* __restrict__ kb, const float* __restrict__ vb,
    const float* __restrict__ xbar, const float* __restrict__ Wq,
    float* __restrict__ ob)
{
  __shared__ float qs[DD];
  __shared__ float ks[NN * 9];  // pad stride 9 (coprime with 32 banks)
  __shared__ float vs[NN * 9];
  const int l = blockIdx.x;
  const int t = threadIdx.x;
  const int h = t >> 6;          // wave id == head
  const int lane = t & 63;

  const float* kl = kb + (size_t)l * NN * DHH;
  const float* vl = vb + (size_t)l * NN * DHH;
#pragma unroll
  for (int i = 0; i < 8; ++i) {
    const int idx = i * 512 + t;
    const int n = idx >> 3, j = idx & 7;
    ks[n*9 + j] = kl[idx];
    vs[n*9 + j] = vl[idx];
  }
  if (t < DD) {
    float acc = 0.f;
    for (int d = 0; d < DD; ++d) acc = fmaf(xbar[l*DD + d], Wq[d*DD + t], acc);
    qs[t] = acc * 0.35355339059327373f;  // 1/sqrt(DH)
  }
  __syncthreads();

  float sc[8];
  float m = -1e30f;
#pragma unroll
  for (int i = 0; i < 8; ++i) {
    const int n = i * 64 + lane;
    float s = 0.f;
#pragma unroll
    for (int d = 0; d < DHH; ++d) s = fmaf(qs[h*DHH + d], ks[n*9 + d], s);
    sc[i] = s;
    m = fmaxf(m, s);
  }
#pragma unroll
  for (int off = 32; off; off >>= 1) m = fmaxf(m, __shfl_xor(m, off));
  float ssum = 0.f;
#pragma unroll
  for (int i = 0; i < 8; ++i) { sc[i] = __expf(sc[i] - m); ssum += sc[i]; }
#pragma unroll
  for (int off = 32; off; off >>= 1) ssum += __shfl_xor(ssum, off);
  const float inv = 1.f / ssum;

  float oacc[DHH];
#pragma unroll
  for (int d = 0; d < DHH; ++d) oacc[d] = 0.f;
#pragma unroll
  for (int i = 0; i < 8; ++i) {
    const int n = i * 64 + lane;
#pragma unroll
    for (int d = 0; d < DHH; ++d) oacc[d] = fmaf(sc[i], vs[n*9 + d], oacc[d]);
  }
#pragma unroll
  for (int d = 0; d < DHH; ++d) {
#pragma unroll
    for (int off = 32; off; off >>= 1) oacc[d] += __shfl_xor(oacc[d], off);
  }
  if (lane == 0) {
    float4* op = (float4*)(ob + (size_t)l * DD + h * DHH);
    op[0] = make_float4(oacc[0]*inv, oacc[1]*inv, oacc[2]*inv, oacc[3]*inv);
    op[1] = make_float4(oacc[4]*inv, oacc[5]*inv, oacc[6]*inv, oacc[7]*inv);
  }
}

// ---------------------------------------------------------------------------
// Kernel C: per row: LN, gate = sigmoid(x@Wg + bg), t = gate*o[l],
// out = t@Wout + bout. 256 consecutive rows per block; rows staged through
// LDS (stride 65 -> (t+d)%32 banks, 2-way = free) so the 64-wide matvecs run
// with register accumulators + wave-uniform (scalar) weight loads.
// ---------------------------------------------------------------------------
__global__ __launch_bounds__(256) void kC(
    const float* __restrict__ msa, const float* __restrict__ lnw, const float* __restrict__ lnb,
    const float* __restrict__ Wg, const float* __restrict__ bgv,
    const float* __restrict__ ob, const float* __restrict__ Wout, const float* __restrict__ bout,
    float* __restrict__ out)
{
  __shared__ float X[256 * 65];  // 66.5 KB
  const int t = threadIdx.x;
  const size_t rowbase = (size_t)blockIdx.x * 256;

  // coalesced stage: tile is 256*64 contiguous floats
  const float4* gp = (const float4*)(msa + rowbase * DD);
#pragma unroll
  for (int i = 0; i < 16; ++i) {
    const int fidx = i * 256 + t;
    const float4 f = gp[fidx];
    const int flt = fidx * 4;
    const int r = flt >> 6, c = flt & 63;
    X[r*65 + c + 0] = f.x; X[r*65 + c + 1] = f.y;
    X[r*65 + c + 2] = f.z; X[r*65 + c + 3] = f.w;
  }
  __syncthreads();

  // LN stats (two-pass, matches reference)
  float s = 0.f;
  for (int d = 0; d < DD; ++d) s += X[t*65 + d];
  const float mu = s * (1.f / DD);
  float s2 = 0.f;
  for (int d = 0; d < DD; ++d) { const float c = X[t*65 + d] - mu; s2 = fmaf(c, c, s2); }
  const float rs = rsqrtf(s2 * (1.f / DD) + EPSF);

  // gate pre-activation: acc[j] = sum_d xn_d * Wg[d][j]
  float acc[DD];
#pragma unroll
  for (int j = 0; j < DD; ++j) acc[j] = 0.f;
  for (int d = 0; d < DD; ++d) {
    const float xn = (X[t*65 + d] - mu) * rs * lnw[d] + lnb[d];
#pragma unroll
    for (int j = 0; j < DD; ++j) acc[j] = fmaf(xn, Wg[d*DD + j], acc[j]);
  }

  // t_j = sigmoid(acc_j + bg_j) * o[l][j], written back into own LDS row
  const int l = (int)((rowbase + t) & (LL - 1));
  const float4* orow = (const float4*)(ob + (size_t)l * DD);
#pragma unroll
  for (int i = 0; i < 16; ++i) {
    const float4 ov = orow[i];
    const int j = 4 * i;
    X[t*65 + j + 0] = ov.x / (1.f + __expf(-(acc[j+0] + bgv[j+0])));
    X[t*65 + j + 1] = ov.y / (1.f + __expf(-(acc[j+1] + bgv[j+1])));
    X[t*65 + j + 2] = ov.z / (1.f + __expf(-(acc[j+2] + bgv[j+2])));
    X[t*65 + j + 3] = ov.w / (1.f + __expf(-(acc[j+3] + bgv[j+3])));
  }

  // out row: acc[j] = bout[j] + sum_d t_d * Wout[d][j]
#pragma unroll
  for (int j = 0; j < DD; ++j) acc[j] = bout[j];
  for (int d = 0; d < DD; ++d) {
    const float td = X[t*65 + d];
#pragma unroll
    for (int j = 0; j < DD; ++j) acc[j] = fmaf(td, Wout[d*DD + j], acc[j]);
  }

  // write own row to LDS, then coalesced transpose-out
#pragma unroll
  for (int j = 0; j < DD; ++j) X[t*65 + j] = acc[j];
  __syncthreads();
  float4* op = (float4*)(out + rowbase * DD);
#pragma unroll
  for (int i = 0; i < 16; ++i) {
    const int fidx = i * 256 + t;
    const int flt = fidx * 4;
    const int r = flt >> 6, c = flt & 63;
    op[fidx] = make_float4(X[r*65 + c + 0], X[r*65 + c + 1],
                           X[r*65 + c + 2], X[r*65 + c + 3]);
  }
}

// ---------------------------------------------------------------------------
extern "C" void kernel_launch(void* const* d_in, const int* in_sizes, int n_in,
                              void* d_out, int out_size, void* d_ws, size_t ws_size,
                              hipStream_t stream)
{
  const float* msa  = (const float*)d_in[0];
  const float* lnw  = (const float*)d_in[1];
  const float* lnb  = (const float*)d_in[2];
  const float* Wq   = (const float*)d_in[3];
  const float* Wk   = (const float*)d_in[4];
  const float* Wv   = (const float*)d_in[5];
  const float* Wg   = (const float*)d_in[6];
  const float* bg   = (const float*)d_in[7];
  const float* Wout = (const float*)d_in[8];
  const float* bout = (const float*)d_in[9];
  float* out = (float*)d_out;

  float* kb   = (float*)d_ws;                       // (L, N, 8) 16 MB
  float* vb   = kb + (size_t)LL * NN * DHH;         // (L, N, 8) 16 MB
  float* xbar = vb + (size_t)LL * NN * DHH;         // (L, 64)  256 KB
  float* ob   = xbar + (size_t)LL * DD;             // (L, 64)  256 KB

  kA<<<LL, 256, 0, stream>>>(msa, lnw, lnb, Wk, Wv, kb, vb, xbar);
  kB<<<LL, 512, 0, stream>>>(kb, vb, xbar, Wq, ob);
  kC<<<(NN * LL) / 256, 256, 0, stream>>>(msa, lnw, lnb, Wg, bg, ob, Wout, bout, out);
}